// Round 13
// baseline (60.424 us; speedup 1.0000x reference)
//
#include <hip/hip_runtime.h>

#define LN2 0.6931471805599453f

typedef float f32x4 __attribute__((ext_vector_type(4)));

// lane i <- lane i-1 (value), lane 0 <- 0.0f   (wave_shr:1)
__device__ __forceinline__ float dpp_shr1_zero(float x) {
    return __int_as_float(__builtin_amdgcn_update_dpp(
        0, __float_as_int(x), 0x138, 0xF, 0xF, true));
}
// lane i <- lane i-1 (int), lane 0 keeps own
__device__ __forceinline__ int dpp_shr1_keep(int x) {
    return __builtin_amdgcn_update_dpp(x, x, 0x138, 0xF, 0xF, false);
}
// lane i <- lane i+1 (value), lane 63 <- 0.0f  (wave_shl:1)
__device__ __forceinline__ float dpp_shl1_zero(float x) {
    return __int_as_float(__builtin_amdgcn_update_dpp(
        0, __float_as_int(x), 0x130, 0xF, 0xF, true));
}
// lane i <- lane i+1 (int), lane 63 keeps own
__device__ __forceinline__ int dpp_shl1_keep(int x) {
    return __builtin_amdgcn_update_dpp(x, x, 0x130, 0xF, 0xF, false);
}
// exact 2^clamp(d, -126, 127)
__device__ __forceinline__ float exp2i_clamped(int d) {
    int k = 127 + d;
    k = (k < 1) ? 1 : ((k > 254) ? 254 : k);
    return __uint_as_float(((unsigned)k) << 23);
}

struct FwdState {
    float a0, a1, a2;   // alpha (linear, scaled by 2^-esum)
    float s1, k0, k1;   // 2^(eL-e), skm0*s1, skm1*s1
    int   esum;
};
struct BwdState {
    float c0, c1, c2;   // gamma = emit*beta (linear, scaled by 2^-esum)
    float s1b, kA, kB;  // 2^(eR-e), sknA*s1b, sknB*s1b
    int   esum;
};

// 11 VALU per step (proven exact R4-R12)
__device__ __forceinline__ void fwd_step(float em0, float em1, float em2,
                                         FwdState& st, float skm2) {
    float d2 = dpp_shr1_zero(st.a2);
    float d1 = dpp_shr1_zero(st.a1);
    float n0 = fmaf(st.k0, d1, fmaf(st.s1, d2, st.a0)) * em0;
    float n1 = fmaf(st.k1, d2, st.a1 + st.a0) * em1;
    float n2 = fmaf(skm2, st.a0, st.a2 + st.a1) * em2;
    st.a0 = n0; st.a1 = n1; st.a2 = n2;
}
// mirror (proven exact R8/R12)
__device__ __forceinline__ void bwd_step(float em0, float em1, float em2,
                                         BwdState& st, float skm2) {
    float d3 = dpp_shl1_zero(st.c0);
    float d4 = dpp_shl1_zero(st.c1);
    float n0 = fmaf(skm2, st.c2, st.c0 + st.c1) * em0;
    float n1 = fmaf(st.kA, d3, st.c1 + st.c2) * em1;
    float n2 = fmaf(st.kB, d4, fmaf(st.s1b, d3, st.c2)) * em2;
    st.c0 = n0; st.c1 = n1; st.c2 = n2;
}

// Every 8 steps (proven exact R6/R12)
__device__ __forceinline__ void fwd_rescale(FwdState& st, float skm0, float skm1) {
    float m = fmaxf(fmaxf(st.a0, st.a1), st.a2);
    int ebits = (int)(__float_as_uint(m) >> 23);
    bool dead = (ebits == 0);
    int de = dead ? 0 : (127 - ebits);
    float scz = dead ? 0.0f : exp2i_clamped(de);
    st.a0 *= scz; st.a1 *= scz; st.a2 *= scz;
    st.esum -= de;
    #pragma unroll
    for (int r = 0; r < 5; ++r) {
        int en = dpp_shr1_keep(st.esum);
        st.esum = dead ? en : st.esum;
    }
    int enf = dpp_shr1_keep(st.esum);
    int gap = enf - st.esum;
    int adj = (gap > 64) ? (gap - 64) : 0;
    float sc3 = exp2i_clamped(-adj);
    st.a0 *= sc3; st.a1 *= sc3; st.a2 *= sc3;
    st.esum += adj;
    st.s1 = exp2i_clamped(gap - adj);
    st.k0 = skm0 * st.s1;
    st.k1 = skm1 * st.s1;
}
// R8-hardened bwd rescale (proven exact R8/R12)
__device__ __forceinline__ void bwd_rescale(BwdState& st, float sknA, float sknB) {
    float m = fmaxf(fmaxf(st.c0, st.c1), st.c2);
    int ebits = (int)(__float_as_uint(m) >> 23);
    bool dead = (ebits == 0);
    int de = dead ? 0 : (127 - ebits);
    float scz = dead ? 0.0f : exp2i_clamped(de);
    st.c0 *= scz; st.c1 *= scz; st.c2 *= scz;
    st.esum -= de;
    #pragma unroll
    for (int r = 0; r < 5; ++r) {
        int en = dpp_shl1_keep(st.esum);
        st.esum = dead ? en : st.esum;
    }
    #pragma unroll
    for (int r = 0; r < 3; ++r) {
        int enl = dpp_shr1_keep(st.esum);
        int mn = (enl < st.esum) ? enl : st.esum;
        st.esum = dead ? mn : st.esum;
    }
    int deadR = dpp_shl1_keep(dead ? 1 : 0);
    int enf = dpp_shl1_keep(st.esum);
    int gap = enf - st.esum;
    int adj = (gap > 64) ? (gap - 64) : 0;
    adj = (adj > 126) ? 126 : adj;
    adj = deadR ? 0 : adj;
    float sc3 = exp2i_clamped(-adj);
    st.c0 *= sc3; st.c1 *= sc3; st.c2 *= sc3;
    st.esum += adj;
    float s1b = exp2i_clamped(gap - adj);
    st.s1b = deadR ? 0.f : s1b;
    st.kA = sknA * st.s1b;
    st.kB = sknB * st.s1b;
}

// Two waves per (b,f): wave 0 = alpha forward rows 1..m, wave 1 = gamma
// backward rows TL-2..m+1. Rows in LDS as {d=p1-p0, p0-pb, pb, 0}; per step
// ONE ds_read_b128 + 5-fma emission reconstruction (R11-proven) + 11-VALU
// recursion. Midpoint combine = R12 epilogue.
__global__ __launch_bounds__(128, 1) void ctc_kernel(
    const float* __restrict__ logits,        // [T, B, 2F+1]
    const int* __restrict__ targets,         // [B, F, S]
    const int* __restrict__ input_lengths,   // [B]
    const int* __restrict__ target_lengths,  // [B, F]
    float* __restrict__ loss_out,            // [B*F] (loss / tl)
    int T, int B, int Ff, int S)
{
    const int p = blockIdx.x;
    const int b = p / Ff;
    const int f = p - b * Ff;
    const int tid = (int)threadIdx.x;
    const int wid = tid >> 6;
    const int lane = tid & 63;
    const int C = 2 * Ff + 1;
    const int L = 2 * S + 1;

    const int tl = target_lengths[p];
    const int il = input_lengths[b];
    const int tbase = p * S;

    // ---- per-lane static metadata: states l = 3*lane + j ----
    // tf_j: target value (0/1) for odd in-range states else 0; skm_j: skip mask.
    float tf0, tf1, tf2, skm0, skm1, skm2;
    {
        float tf[3], sk[3];
        const int l0 = 3 * lane;
        #pragma unroll
        for (int j = 0; j < 3; ++j) {
            int l = l0 + j;
            float tv = 0.f, sok = 0.f;
            if (l < L && (l & 1)) {
                int s = (l - 1) >> 1;
                int ev = targets[tbase + s];
                tv = (float)ev;
                if (s >= 1) sok = (targets[tbase + s - 1] != ev) ? 1.f : 0.f;
            }
            tf[j] = tv; sk[j] = sok;
        }
        tf0 = tf[0]; tf1 = tf[1]; tf2 = tf[2];
        skm0 = sk[0]; skm1 = sk[1]; skm2 = sk[2];
    }
    const float sknA = dpp_shl1_zero(skm0);   // skip_ok(l0+3)
    const float sknB = dpp_shl1_zero(skm1);   // skip_ok(l0+4)
    const float vP = (float)(lane & 1);       // parity of states l0, l0+2
    const float vQ = 1.0f - vP;               // parity of state l0+1

    // ---- stage rows into LDS: slp[t] = {p1-p0, p0-pb, pb, 0} ----
    __shared__ f32x4 slp[640];                // zero-padded past T
    {
        const float* lg = logits + (size_t)b * C;
        const size_t strideT = (size_t)B * C;
        float c0 = 0.f, c1 = 0.f, c2 = 0.f;
        if (tid < T) {
            const float* r = lg + (size_t)tid * strideT;
            c0 = r[f]; c1 = r[Ff + f]; c2 = r[2 * Ff];
        }
        #pragma unroll 1
        for (int j = 0; j < 5; ++j) {         // 5*128 = 640
            int i = tid + (j << 7);
            int inx = i + 128;
            float n0 = 0.f, n1 = 0.f, n2 = 0.f;
            if (inx < T) {
                const float* r = lg + (size_t)inx * strideT;
                n0 = r[f]; n1 = r[Ff + f]; n2 = r[2 * Ff];
            }
            f32x4 v = {0.f, 0.f, 0.f, 0.f};
            if (i < T) {
                float m = fmaxf(fmaxf(c0, c1), c2);
                float ep = __expf(c0 - m);
                float en = __expf(c1 - m);
                float eb = __expf(c2 - m);
                float inv = __builtin_amdgcn_rcpf(ep + en + eb);
                float p0 = ep * inv, p1 = en * inv, pb = eb * inv;
                v[0] = p1 - p0; v[1] = p0 - pb; v[2] = pb;
            }
            if (i < 640) slp[i] = v;
            c0 = n0; c1 = n1; c2 = n2;
        }
    }
    __syncthreads();

    const int TL = (il < T) ? il : T;
    const int m_ = (TL >= 2) ? ((TL - 1) >> 1) : 0;
    const int Fn = m_;                               // fwd steps: rows 1..m_
    const int Bk = (TL >= 2) ? (TL - 2 - m_) : 0;    // bwd steps: rows TL-2..m_+1

    // ---- epilogue shared buffers ----
    __shared__ float sa[192];
    __shared__ float sg[194];
    __shared__ int   seb[65];
    __shared__ float sdot[64];
    __shared__ int   sE[64];

    // emission reconstruction: e_j = tf_j*d + (parity_j ? dpb : 0) + pb
#define EMF(E, EV0, EV1, EV2) \
    float iA = fmaf(vP, (E)[1], (E)[2]); \
    float iB = fmaf(vQ, (E)[1], (E)[2]); \
    float EV0 = fmaf(tf0, (E)[0], iA); \
    float EV1 = fmaf(tf1, (E)[0], iB); \
    float EV2 = fmaf(tf2, (E)[0], iA);

    FwdState fs;
    fs.a0 = 0.f; fs.a1 = 0.f; fs.a2 = 0.f; fs.s1 = 1.f;
    fs.k0 = skm0; fs.k1 = skm1; fs.esum = 0;

    if (wid == 0) {
        // ================= FORWARD WAVE =================
        {
            f32x4 E0 = slp[0];
            float e1i0 = fmaf(tf1, E0[0], E0[1] + E0[2]);  // em(state1) @ row0
            fs.a0 = (lane == 0) ? E0[2] : 0.f;             // state 0 = blank
            fs.a1 = (lane == 0 && tl > 0) ? e1i0 : 0.f;
            fs.a2 = 0.f;
        }
        const int t_endF = Fn + 1;                   // process t = 1..Fn
        int t = 1;
#define FSTEP(IDX) { f32x4 E = slp[(IDX)]; EMF(E, e0, e1, e2) \
                     fwd_step(e0, e1, e2, fs, skm2); }
        #pragma unroll 1
        for (; t + 16 <= t_endF; t += 16) {
            fwd_rescale(fs, skm0, skm1);
            FSTEP(t)      FSTEP(t + 1)  FSTEP(t + 2)  FSTEP(t + 3)
            FSTEP(t + 4)  FSTEP(t + 5)  FSTEP(t + 6)  FSTEP(t + 7)
            fwd_rescale(fs, skm0, skm1);
            FSTEP(t + 8)  FSTEP(t + 9)  FSTEP(t + 10) FSTEP(t + 11)
            FSTEP(t + 12) FSTEP(t + 13) FSTEP(t + 14) FSTEP(t + 15)
        }
        #pragma unroll 1
        for (; t < t_endF; ++t) FSTEP(t)
#undef FSTEP
        {
            int l = 3 * lane;
            sa[l] = fs.a0; sa[l + 1] = fs.a1; sa[l + 2] = fs.a2;
        }
    } else {
        // ================= BACKWARD WAVE =================
        BwdState bs;
        {
            f32x4 EL = slp[TL - 1];
            EMF(EL, eL0, eL1, eL2)
            int l0i = 3 * lane;
            int end1 = 2 * tl, end2 = 2 * tl - 1;
            bs.c0 = (l0i == end1 || l0i == end2) ? eL0 : 0.f;
            bs.c1 = (l0i + 1 == end1 || l0i + 1 == end2) ? eL1 : 0.f;
            bs.c2 = (l0i + 2 == end1 || l0i + 2 == end2) ? eL2 : 0.f;
            bs.s1b = 1.f; bs.kA = sknA; bs.kB = sknB;
            bs.esum = 0;
        }
        int k = 0;
        int tr = TL - 2;
#define BSTEP(IDX) { f32x4 E = slp[(IDX)]; EMF(E, e0, e1, e2) \
                     bwd_step(e0, e1, e2, bs, skm2); }
        #pragma unroll 1
        for (; k + 16 <= Bk; k += 16, tr -= 16) {
            bwd_rescale(bs, sknA, sknB);
            BSTEP(tr)      BSTEP(tr - 1)  BSTEP(tr - 2)  BSTEP(tr - 3)
            BSTEP(tr - 4)  BSTEP(tr - 5)  BSTEP(tr - 6)  BSTEP(tr - 7)
            bwd_rescale(bs, sknA, sknB);
            BSTEP(tr - 8)  BSTEP(tr - 9)  BSTEP(tr - 10) BSTEP(tr - 11)
            BSTEP(tr - 12) BSTEP(tr - 13) BSTEP(tr - 14) BSTEP(tr - 15)
        }
        #pragma unroll 1
        for (; k < Bk; ++k, --tr) BSTEP(tr)
#undef BSTEP
        {
            int l = 3 * lane;
            sg[l] = bs.c0; sg[l + 1] = bs.c1; sg[l + 2] = bs.c2;
            seb[lane] = bs.esum;
            if (lane == 0) { sg[192] = 0.f; sg[193] = 0.f; seb[64] = 0; }
        }
    }
    __syncthreads();

    // ---- midpoint combine (R12 epilogue, proven) ----
    if (wid == 0) {
        int eB = seb[lane];
        float scn = exp2i_clamped(seb[lane + 1] - eB);
        float g0 = sg[3 * lane], g1 = sg[3 * lane + 1], g2 = sg[3 * lane + 2];
        float g3 = sg[3 * lane + 3] * scn;
        float g4 = sg[3 * lane + 4] * scn;
        float s0 = fmaf(skm2, g2, g0 + g1);
        float s1v = fmaf(sknA, g3, g1 + g2);
        float s2v = fmaf(sknB, g4, g2 + g3);
        float dot = fs.a0 * s0 + fs.a1 * s1v + fs.a2 * s2v;
        sdot[lane] = dot;
        sE[lane] = fs.esum + eB;
    }
    __syncthreads();
    if (tid == 0) {
        float loss = 0.f;
        if (TL == 1) {
            float v = sa[2 * tl] + ((tl > 0) ? sa[2 * tl - 1] : 0.f);
            if (v > 0.f) loss = -(__log2f(v) * LN2);
        } else {
            int Emax = -0x40000000;
            for (int i = 0; i < 64; ++i)
                if (sdot[i] > 0.f && sE[i] > Emax) Emax = sE[i];
            if (Emax != -0x40000000) {
                float sum = 0.f;
                for (int i = 0; i < 64; ++i) {
                    int d = sE[i] - Emax;
                    if (d > -127 && sdot[i] > 0.f) sum += sdot[i] * exp2i_clamped(d);
                }
                loss = -((__log2f(sum) + (float)Emax) * LN2);
            }
        }
        float denom = (tl > 0) ? (float)tl : 1.0f;
        loss_out[p] = loss / denom;
    }
#undef EMF
}

// Deterministic single-block reduction: out[0] = sum(v) / B
__global__ __launch_bounds__(256) void reduce_kernel(
    const float* __restrict__ v, float* __restrict__ out, int n, float invB)
{
    __shared__ float buf[256];
    float s = 0.f;
    for (int i = (int)threadIdx.x; i < n; i += 256) s += v[i];
    buf[threadIdx.x] = s;
    __syncthreads();
    for (int off = 128; off > 0; off >>= 1) {
        if ((int)threadIdx.x < off) buf[threadIdx.x] += buf[threadIdx.x + off];
        __syncthreads();
    }
    if (threadIdx.x == 0) out[0] = buf[0] * invB;
}

extern "C" void kernel_launch(void* const* d_in, const int* in_sizes, int n_in,
                              void* d_out, int out_size, void* d_ws, size_t ws_size,
                              hipStream_t stream) {
    const float* logits         = (const float*)d_in[0];
    const int*   targets        = (const int*)d_in[1];
    const int*   input_lengths  = (const int*)d_in[2];
    const int*   target_lengths = (const int*)d_in[3];
    float* out = (float*)d_out;

    const int B  = in_sizes[2];            // 32
    const int BF = in_sizes[3];            // B*F = 1120
    const int Ff = BF / B;                 // 35
    const int S  = in_sizes[1] / BF;       // 80
    const int C  = 2 * Ff + 1;             // 71
    const int T  = in_sizes[0] / (B * C);  // 600

    float* losses = (float*)d_ws;          // BF floats of scratch

    ctc_kernel<<<BF, 128, 0, stream>>>(logits, targets, input_lengths,
                                       target_lengths, losses, T, B, Ff, S);
    reduce_kernel<<<1, 256, 0, stream>>>(losses, out, BF, 1.0f / (float)B);
}